// Round 14
// baseline (257.922 us; speedup 1.0000x reference)
//
#include <hip/hip_runtime.h>

// B=4, N=10, C=256, Lq=Ls=1024, K=5, G=2.  TQ=64, TS=32.  fp16 MFMA path.
#define CQ_ELEMS (4 * 256 * 1024)
#define CS_ELEMS (10 * 256 * 1024)
#define OUT2_OFF 2097152

typedef __attribute__((ext_vector_type(8))) _Float16 f16x8;
typedef __attribute__((ext_vector_type(4))) float f32x4;

// ws layout (bytes): [0..255] float means[2];
//   Sh[n][s][c] fp16, Sv[n][c][s] fp16, Qt[b][q][c] fp16
#define WS_SH 256
#define SH_ELEMS (10 * 1024 * 256)
#define SV_ELEMS (10 * 256 * 1024)

// direct global->LDS DMA, 16 B per lane; LDS dest = wave-uniform base + lane*16
__device__ __forceinline__ void gload_lds16(const unsigned short* g, unsigned short* l) {
    __builtin_amdgcn_global_load_lds(
        (const __attribute__((address_space(1))) void*)g,
        (__attribute__((address_space(3))) void*)l, 16, 0, 0);
}

// ---------------------------------------------------------------------------
__global__ __launch_bounds__(256) void means_kernel(const float* __restrict__ q,
                                                    const float* __restrict__ s,
                                                    float* __restrict__ ws) {
    const int tid = blockIdx.x * 256 + threadIdx.x;
    const int stride = gridDim.x * 256;
    float sq = 0.f, ss = 0.f;
    const float4* q4 = (const float4*)q;
    const float4* s4 = (const float4*)s;
    for (int i = tid; i < CQ_ELEMS / 4; i += stride) {
        float4 v = q4[i];
        sq += (v.x + v.y) + (v.z + v.w);
    }
    for (int i = tid; i < CS_ELEMS / 4; i += stride) {
        float4 v = s4[i];
        ss += (v.x + v.y) + (v.z + v.w);
    }
#pragma unroll
    for (int off = 32; off > 0; off >>= 1) {
        sq += __shfl_down(sq, off, 64);
        ss += __shfl_down(ss, off, 64);
    }
    __shared__ float redq[4], reds[4];
    const int lane = threadIdx.x & 63, wid = threadIdx.x >> 6;
    if (lane == 0) { redq[wid] = sq; reds[wid] = ss; }
    __syncthreads();
    if (threadIdx.x == 0) {
        atomicAdd(&ws[0], (redq[0] + redq[1]) + (redq[2] + redq[3]));
        atomicAdd(&ws[1], (reds[0] + reds[1]) + (reds[2] + reds[3]));
    }
}

// ---------------------------------------------------------------------------
// Centered fp16 conversion.  z<10: S -> Sv [c][s] + Sh [s][c] + zero out2.
// z>=10: Q -> q_out (fp32, both g-copies) + Qt [q][c].
// ---------------------------------------------------------------------------
__global__ __launch_bounds__(256) void convert_kernel(const float* __restrict__ Q,
                                                      const float* __restrict__ S,
                                                      const float* __restrict__ ws,
                                                      unsigned short* __restrict__ sh,
                                                      unsigned short* __restrict__ sv,
                                                      unsigned short* __restrict__ qt,
                                                      float* __restrict__ out) {
    __shared__ unsigned short Th[32][40];
    const int t = threadIdx.x;
    const int x0 = blockIdx.x << 5;   // s (or q) tile base
    const int c0 = blockIdx.y << 5;   // c tile base
    const int z = blockIdx.z;

    const int cl = t >> 3, x4 = (t & 7) << 2;

    if (z < 10) {
        const int n = z;
        const float ms = ws[1] * (1.0f / (float)CS_ELEMS);
        float4 v = *(const float4*)(S + ((size_t)(n * 256 + c0 + cl)) * 1024 + x0 + x4);
        float x[4] = {v.x - ms, v.y - ms, v.z - ms, v.w - ms};
        unsigned short hb[4];
#pragma unroll
        for (int j = 0; j < 4; ++j) {
            _Float16 h = (_Float16)x[j];
            hb[j] = __builtin_bit_cast(unsigned short, h);
            Th[cl][x4 + j] = hb[j];
        }
        *(ushort4*)(sv + ((size_t)(n * 256 + c0 + cl)) * 1024 + x0 + x4) =
            make_ushort4(hb[0], hb[1], hb[2], hb[3]);
        // zero the atomically-accumulated 'aligned' half of d_out (8 MB over 2560 blocks)
        {
            const int lin = (z * 8 + blockIdx.y) * 32 + blockIdx.x;
            const int gid = lin * 256 + t;
            if (gid < 524288) ((int4*)(out + OUT2_OFF))[gid] = make_int4(0, 0, 0, 0);
        }
        __syncthreads();
        const int sl = t >> 3, c4 = (t & 7) << 2;
        *(ushort4*)(sh + ((size_t)(n * 1024 + x0 + sl)) * 256 + c0 + c4) =
            make_ushort4(Th[c4 + 0][sl], Th[c4 + 1][sl], Th[c4 + 2][sl], Th[c4 + 3][sl]);
    } else {
        const int b = z - 10;
        const float mq = ws[0] * (1.0f / (float)CQ_ELEMS);
        float4 v = *(const float4*)(Q + ((size_t)(b * 256 + c0 + cl)) * 1024 + x0 + x4);
        v.x -= mq; v.y -= mq; v.z -= mq; v.w -= mq;
        float* o = out + ((size_t)(b * 2) * 256 + (c0 + cl)) * 1024 + x0 + x4;
        *(float4*)o = v;
        *(float4*)(o + 256 * 1024) = v;
        float x[4] = {v.x, v.y, v.z, v.w};
#pragma unroll
        for (int j = 0; j < 4; ++j) {
            _Float16 h = (_Float16)x[j];
            Th[cl][x4 + j] = __builtin_bit_cast(unsigned short, h);
        }
        __syncthreads();
        const int ql = t >> 3, c4 = (t & 7) << 2;
        *(ushort4*)(qt + ((size_t)(b * 1024 + x0 + ql)) * 256 + c0 + c4) =
            make_ushort4(Th[c4 + 0][ql], Th[c4 + 1][ql], Th[c4 + 2][ql], Th[c4 + 3][ql]);
    }
}

// ---------------------------------------------------------------------------
// Fused flash attention, fp16 MFMA, DMA staging.  = R10's verified 2-barrier
// lockstep schedule (113 us) with a C-SPLIT for occupancy: grid 1280, each
// (qx,b,n) pair handled by TWO blocks h=0/1, block h owning PV c-range
// [128h, 128h+128).  R12 post-mortem: occupancy was GRID-limited (640 blocks
// = 2.5/CU, 23%); every schedule-overlap attempt regressed (R3/R5/R9/R12),
// so TLP must come from more blocks.  QK^T+softmax is duplicated per pair --
// that costs only idle MFMA/VALU (17%/27% busy) and L2-resident s1 re-reads
// (same XCD by construction), NOT HBM.  s2 stages only the block's 128
// c-rows (8 KB).  out2 atomics are disjoint in c; Lsum is c-independent
// (duplicated).  LDS 33792 B + __launch_bounds__(256,4) -> 4 blocks/CU cap.
//
// (1) XCD-affinity block swizzle: all 128 blocks sharing support-stream n
//     land on one XCD (FETCH 48.8 -> 16.4 MB, verified R7).
// (2) Row-sum folded into PV as a ones-channel MFMA (Lsum).
//
// s1 (16 KB): frag-major.  slot16 p = (f*2+nt)*64 + quad*16 + l16 holds
//   Sh[s0 + 2*l16 + nt][f*32 + quad*8 .. +7].
// s2 (8 KB): slot16 p holds V^T[local c = p>>2][chunk = (p&3)^((c>>2)&3)],
//   local c = global c - 128h; read p = c*4 + (quad ^ ((l16>>2)&3)) -> 2-way.
// pb: P [q][s] 80 B rows; alpha at cols 32-33.
// ---------------------------------------------------------------------------
union __align__(16) SMem {
    struct {
        unsigned short s1[8192];     // 16 KB
        unsigned short s2[4096];     // 8 KB (this block's 128 c-rows)
        unsigned short pb[64][40];   // 5 KB (cols 32-33: alpha float)
    } st;                            // 29696 B
    float epi[128][66];              // 33792 B, aliases st at epilogue
};

__global__ __launch_bounds__(256, 4) void attn_kernel(const unsigned short* __restrict__ qt,
                                                      const unsigned short* __restrict__ sh,
                                                      const unsigned short* __restrict__ sv,
                                                      float* __restrict__ out) {
    __shared__ SMem sm;

    const int t = threadIdx.x;
    const int w = t >> 6;
    const int lane = t & 63;
    const int quad = lane >> 4;
    const int l16 = lane & 15;

    // ---- XCD-affinity decode: all blocks of a given n on one XCD ----
    int qx, b, n, h;
    {
        const int L = blockIdx.x;          // 0..1279
        if (L < 1024) {
            n = L & 7;                     // XCD = L % 8 = n
            const int inner = L >> 3;      // 0..127
            h = inner & 1;
            b = (inner >> 1) & 3;
            qx = inner >> 3;               // 0..15
        } else {
            const int r = L - 1024;        // 0..255
            const int x = r & 7;           // XCD
            n = 8 + (x >> 2);              // 8 on XCD 0-3, 9 on XCD 4-7
            const int combo = (x & 3) * 32 + (r >> 3);   // 0..127
            h = combo & 1;
            b = (combo >> 1) & 3;
            qx = combo >> 3;
        }
    }
    const int q0 = qx << 6;
    const int g = n / 5;

    const unsigned short* __restrict__ Shn = sh + (size_t)n * (1024 * 256);
    const unsigned short* __restrict__ Svn = sv + (size_t)n * (256 * 1024);

    // ---- Q A-frags: wave w owns q rows q0+16w .. +15 ----
    f16x8 qf[8];
    {
        const unsigned short* qp = qt + (size_t)(b * 1024 + q0 + 16 * w + l16) * 256 + quad * 8;
#pragma unroll
        for (int f = 0; f < 8; ++f)
            qf[f] = *(const f16x8*)(qp + f * 32);
    }

    // ones A-frag for the row-sum channel
    f16x8 onesA;
#pragma unroll
    for (int j = 0; j < 8; ++j) onesA[j] = (_Float16)1.0f;

    f32x4 O[2][4];   // O^T: local c = 32w+16mt+4quad+r (global +128h), q = 16nt+l16
#pragma unroll
    for (int mt = 0; mt < 2; ++mt)
#pragma unroll
        for (int nt = 0; nt < 4; ++nt) O[mt][nt] = (f32x4){0.f, 0.f, 0.f, 0.f};

    f32x4 Lsum[4];   // row-sum channel: Lsum[nt][*] = sum_s P[q=16nt+l16][s]
#pragma unroll
    for (int nt = 0; nt < 4; ++nt) Lsum[nt] = (f32x4){0.f, 0.f, 0.f, 0.f};

    float m_run[4];
#pragma unroll
    for (int r = 0; r < 4; ++r) m_run[r] = -1e30f;

    for (int s0i = 0; s0i < 32; ++s0i) {
        const int s0 = s0i << 5;

        // ---- DMA-stage s1 (4 groups/wave) and s2 (2 groups/wave) ----
#pragma unroll
        for (int j = 0; j < 4; ++j) {
            const int fidx = 4 * w + j;
            const unsigned short* g1 = Shn +
                (size_t)(s0 + 2 * (lane & 15) + (fidx & 1)) * 256 + (fidx >> 1) * 32 + (lane >> 4) * 8;
            gload_lds16(g1, &sm.st.s1[fidx * 512]);
        }
#pragma unroll
        for (int j = 0; j < 2; ++j) {
            const int fidx = 2 * w + j;
            const unsigned short* g2 = Svn +
                (size_t)(128 * h + w * 32 + j * 16 + (lane >> 2)) * 1024 + s0 + ((lane & 3) ^ (lane >> 4)) * 8;
            gload_lds16(g2, &sm.st.s2[fidx * 512]);
        }
        __syncthreads();   // B: drains vmcnt -> tiles ready; fences pb(t-1) reads vs writes

        // ---- QK^T: sim[16q x 32s] ----
        f32x4 sim0 = (f32x4){0.f, 0.f, 0.f, 0.f};
        f32x4 sim1 = (f32x4){0.f, 0.f, 0.f, 0.f};
#pragma unroll
        for (int f = 0; f < 8; ++f) {
            const unsigned short* base = &sm.st.s1[f * 1024 + quad * 128 + l16 * 8];
            f16x8 b0 = *(const f16x8*)base;           // nt=0: true s = 2*l16
            f16x8 b1 = *(const f16x8*)(base + 512);   // nt=1: true s = 2*l16+1
            sim0 = __builtin_amdgcn_mfma_f32_16x16x32_f16(qf[f], b0, sim0, 0, 0, 0);
            sim1 = __builtin_amdgcn_mfma_f32_16x16x32_f16(qf[f], b1, sim1, 0, 0, 0);
        }

        // ---- online softmax, max only (rows q = 16w+4quad+r; reduce over l16) ----
        float rowmax[4];
#pragma unroll
        for (int r = 0; r < 4; ++r) rowmax[r] = fmaxf(sim0[r], sim1[r]);
#pragma unroll
        for (int off = 1; off <= 8; off <<= 1)
#pragma unroll
            for (int r = 0; r < 4; ++r)
                rowmax[r] = fmaxf(rowmax[r], __shfl_xor(rowmax[r], off, 64));

        float al[4], pv0[4], pv1[4];
#pragma unroll
        for (int r = 0; r < 4; ++r) {
            const float mn = fmaxf(m_run[r], rowmax[r]);
            al[r] = __expf(m_run[r] - mn);
            m_run[r] = mn;
            pv0[r] = __expf(sim0[r] - mn);
            pv1[r] = __expf(sim1[r] - mn);
        }

        // ---- publish P (fp16 pairs, b32) and alpha (pb cols 32-33) ----
#pragma unroll
        for (int r = 0; r < 4; ++r) {
            union { _Float16 hh[2]; unsigned u; } pk;
            pk.hh[0] = (_Float16)pv0[r];
            pk.hh[1] = (_Float16)pv1[r];
            *(unsigned*)&sm.st.pb[16 * w + 4 * quad + r][l16 * 2] = pk.u;
        }
        if (l16 == 0) {
#pragma unroll
            for (int r = 0; r < 4; ++r)
                *(float*)&sm.st.pb[16 * w + 4 * quad + r][32] = al[r];
        }
        __syncthreads();   // C: P ready

        // ---- rescale O^T and Lsum, then O^T += V^T * P^T; Lsum += ones * P^T ----
#pragma unroll
        for (int nt = 0; nt < 4; ++nt) {
            const float a = *(const float*)&sm.st.pb[16 * nt + l16][32];
#pragma unroll
            for (int mt = 0; mt < 2; ++mt) {
                O[mt][nt][0] *= a; O[mt][nt][1] *= a; O[mt][nt][2] *= a; O[mt][nt][3] *= a;
            }
            Lsum[nt][0] *= a; Lsum[nt][1] *= a; Lsum[nt][2] *= a; Lsum[nt][3] *= a;
        }
        f16x8 vf[2], pf[4];
#pragma unroll
        for (int mt = 0; mt < 2; ++mt) {
            const int c = 32 * w + 16 * mt + l16;            // local c
            const int p = c * 4 + (quad ^ ((l16 >> 2) & 3));
            vf[mt] = *(const f16x8*)&sm.st.s2[p * 8];
        }
#pragma unroll
        for (int nt = 0; nt < 4; ++nt)
            pf[nt] = *(const f16x8*)&sm.st.pb[16 * nt + l16][quad * 8];
#pragma unroll
        for (int mt = 0; mt < 2; ++mt)
#pragma unroll
            for (int nt = 0; nt < 4; ++nt)
                O[mt][nt] = __builtin_amdgcn_mfma_f32_16x16x32_f16(vf[mt], pf[nt], O[mt][nt], 0, 0, 0);
#pragma unroll
        for (int nt = 0; nt < 4; ++nt)
            Lsum[nt] = __builtin_amdgcn_mfma_f32_16x16x32_f16(onesA, pf[nt], Lsum[nt], 0, 0, 0);
    }

    // all final pb/s2 reads done before epi aliases them
    __syncthreads();

    // ---- epilogue: denominator in registers (Lsum), no LDS publish ----
    float linv[4];
#pragma unroll
    for (int nt = 0; nt < 4; ++nt)
        linv[nt] = 0.2f / Lsum[nt][0];

    float* __restrict__ out2 = out + OUT2_OFF + (size_t)((g << 2) + b) * (256 * 1024);

    // write epi[local c][q], then disjoint atomics for c = 128h + local
#pragma unroll
    for (int mt = 0; mt < 2; ++mt)
#pragma unroll
        for (int nt = 0; nt < 4; ++nt)
#pragma unroll
            for (int r = 0; r < 4; ++r)
                sm.epi[32 * w + 16 * mt + 4 * quad + r][16 * nt + l16] = O[mt][nt][r] * linv[nt];
    __syncthreads();
#pragma unroll 4
    for (int i = 0; i < 32; ++i) {
        const int ro = w * 32 + i;   // 0..127 local c
        atomicAdd(out2 + (size_t)(128 * h + ro) * 1024 + q0 + lane, sm.epi[ro][lane]);
    }
}

// ---------------------------------------------------------------------------
extern "C" void kernel_launch(void* const* d_in, const int* in_sizes, int n_in,
                              void* d_out, int out_size, void* d_ws, size_t ws_size,
                              hipStream_t stream) {
    const float* q = (const float*)d_in[0];
    const float* s = (const float*)d_in[1];
    float* out = (float*)d_out;
    float* ws = (float*)d_ws;
    unsigned short* sh = (unsigned short*)((char*)d_ws + WS_SH);
    unsigned short* sv = sh + SH_ELEMS;
    unsigned short* qt = sv + SV_ELEMS;

    hipMemsetAsync(d_ws, 0, 2 * sizeof(float), stream);

    means_kernel<<<256, 256, 0, stream>>>(q, s, ws);
    convert_kernel<<<dim3(32, 8, 14), 256, 0, stream>>>(q, s, ws, sh, sv, qt, out);
    attn_kernel<<<1280, 256, 0, stream>>>(qt, sh, sv, out);
}

// Round 20
// 219.185 us; speedup vs baseline: 1.1767x; 1.1767x over previous
//
#include <hip/hip_runtime.h>

// B=4, N=10, C=256, Lq=Ls=1024, K=5, G=2.  TQ=64, TS=64, fp16 MFMA path.
#define CQ_ELEMS (4 * 256 * 1024)
#define CS_ELEMS (10 * 256 * 1024)
#define OUT2_OFF 2097152

typedef __attribute__((ext_vector_type(8))) _Float16 f16x8;
typedef __attribute__((ext_vector_type(4))) float f32x4;

// ws layout (bytes): [0..255] float means[2];
//   Sh[n][s][c] fp16, Sv[n][c][s] fp16, Qt[b][q][c] fp16
#define WS_SH 256
#define SH_ELEMS (10 * 1024 * 256)
#define SV_ELEMS (10 * 256 * 1024)

// direct global->LDS DMA, 16 B per lane; LDS dest = wave-uniform base + lane*16
__device__ __forceinline__ void gload_lds16(const unsigned short* g, unsigned short* l) {
    __builtin_amdgcn_global_load_lds(
        (const __attribute__((address_space(1))) void*)g,
        (__attribute__((address_space(3))) void*)l, 16, 0, 0);
}

// ---------------------------------------------------------------------------
__global__ __launch_bounds__(256) void means_kernel(const float* __restrict__ q,
                                                    const float* __restrict__ s,
                                                    float* __restrict__ ws) {
    const int tid = blockIdx.x * 256 + threadIdx.x;
    const int stride = gridDim.x * 256;
    float sq = 0.f, ss = 0.f;
    const float4* q4 = (const float4*)q;
    const float4* s4 = (const float4*)s;
    for (int i = tid; i < CQ_ELEMS / 4; i += stride) {
        float4 v = q4[i];
        sq += (v.x + v.y) + (v.z + v.w);
    }
    for (int i = tid; i < CS_ELEMS / 4; i += stride) {
        float4 v = s4[i];
        ss += (v.x + v.y) + (v.z + v.w);
    }
#pragma unroll
    for (int off = 32; off > 0; off >>= 1) {
        sq += __shfl_down(sq, off, 64);
        ss += __shfl_down(ss, off, 64);
    }
    __shared__ float redq[4], reds[4];
    const int lane = threadIdx.x & 63, wid = threadIdx.x >> 6;
    if (lane == 0) { redq[wid] = sq; reds[wid] = ss; }
    __syncthreads();
    if (threadIdx.x == 0) {
        atomicAdd(&ws[0], (redq[0] + redq[1]) + (redq[2] + redq[3]));
        atomicAdd(&ws[1], (reds[0] + reds[1]) + (reds[2] + reds[3]));
    }
}

// ---------------------------------------------------------------------------
// Centered fp16 conversion.  z<10: S -> Sv [c][s] + Sh [s][c] + zero out2.
// z>=10: Q -> q_out (fp32, both g-copies) + Qt [q][c].
// ---------------------------------------------------------------------------
__global__ __launch_bounds__(256) void convert_kernel(const float* __restrict__ Q,
                                                      const float* __restrict__ S,
                                                      const float* __restrict__ ws,
                                                      unsigned short* __restrict__ sh,
                                                      unsigned short* __restrict__ sv,
                                                      unsigned short* __restrict__ qt,
                                                      float* __restrict__ out) {
    __shared__ unsigned short Th[32][40];
    const int t = threadIdx.x;
    const int x0 = blockIdx.x << 5;   // s (or q) tile base
    const int c0 = blockIdx.y << 5;   // c tile base
    const int z = blockIdx.z;

    const int cl = t >> 3, x4 = (t & 7) << 2;

    if (z < 10) {
        const int n = z;
        const float ms = ws[1] * (1.0f / (float)CS_ELEMS);
        float4 v = *(const float4*)(S + ((size_t)(n * 256 + c0 + cl)) * 1024 + x0 + x4);
        float x[4] = {v.x - ms, v.y - ms, v.z - ms, v.w - ms};
        unsigned short hb[4];
#pragma unroll
        for (int j = 0; j < 4; ++j) {
            _Float16 h = (_Float16)x[j];
            hb[j] = __builtin_bit_cast(unsigned short, h);
            Th[cl][x4 + j] = hb[j];
        }
        *(ushort4*)(sv + ((size_t)(n * 256 + c0 + cl)) * 1024 + x0 + x4) =
            make_ushort4(hb[0], hb[1], hb[2], hb[3]);
        // zero the atomically-accumulated 'aligned' half of d_out (8 MB over 2560 blocks)
        {
            const int lin = (z * 8 + blockIdx.y) * 32 + blockIdx.x;
            const int gid = lin * 256 + t;
            if (gid < 524288) ((int4*)(out + OUT2_OFF))[gid] = make_int4(0, 0, 0, 0);
        }
        __syncthreads();
        const int sl = t >> 3, c4 = (t & 7) << 2;
        *(ushort4*)(sh + ((size_t)(n * 1024 + x0 + sl)) * 256 + c0 + c4) =
            make_ushort4(Th[c4 + 0][sl], Th[c4 + 1][sl], Th[c4 + 2][sl], Th[c4 + 3][sl]);
    } else {
        const int b = z - 10;
        const float mq = ws[0] * (1.0f / (float)CQ_ELEMS);
        float4 v = *(const float4*)(Q + ((size_t)(b * 256 + c0 + cl)) * 1024 + x0 + x4);
        v.x -= mq; v.y -= mq; v.z -= mq; v.w -= mq;
        float* o = out + ((size_t)(b * 2) * 256 + (c0 + cl)) * 1024 + x0 + x4;
        *(float4*)o = v;
        *(float4*)(o + 256 * 1024) = v;
        float x[4] = {v.x, v.y, v.z, v.w};
#pragma unroll
        for (int j = 0; j < 4; ++j) {
            _Float16 h = (_Float16)x[j];
            Th[cl][x4 + j] = __builtin_bit_cast(unsigned short, h);
        }
        __syncthreads();
        const int ql = t >> 3, c4 = (t & 7) << 2;
        *(ushort4*)(qt + ((size_t)(b * 1024 + x0 + ql)) * 256 + c0 + c4) =
            make_ushort4(Th[c4 + 0][ql], Th[c4 + 1][ql], Th[c4 + 2][ql], Th[c4 + 3][ql]);
    }
}

// ---------------------------------------------------------------------------
// Fused flash attention, fp16 MFMA, DMA staging.  = R10's verified 2-barrier
// lockstep schedule (113 us) with TS doubled 32 -> 64: 16 iterations, 32
// barriers/block instead of 64.  R14 post-mortem: per-iteration convoy/drain
// overhead (~6K cyc) dominates the ~2.5K ideal chain, and work-duplication
// TLP levers (R6/R14) fail; halving the OVERHEAD COUNT with identical total
// compute is the remaining lever.  Schedule, layouts, XCD swizzle, Lsum fold
// and epilogue are carried over unchanged; only the s-width scales.
// Cost: LDS 37888 -> 74752 B -> 2 blocks/CU (deliberate trade).
//
// (1) XCD-affinity block swizzle: all 64 blocks sharing support-stream n land
//     on one XCD (FETCH 48.8 -> 16.4 MB, verified R7).
// (2) Row-sum folded into PV as a ones-channel MFMA (Lsum).
//
// s1 (32 KB): frag-major, 32 groups.  fidx = half*16 + f*2 + nt; slot16
//   p = fidx*64 + quad*16 + l16 holds Sh[s0 + 32*half + 2*l16 + nt]
//   [f*32 + quad*8 .. +7].  Waves 0,1 stage half A (s 0..31), waves 2,3
//   half B (s 32..63).
// s2 (32 KB): slot16 p holds V^T[c = p>>3][chunk = (p&7) ^ (c&7)] (chunk =
//   8 s-values); read p = c*8 + ((ks*4+quad) ^ (c&7)) -> 2-way (free).
//   Per-wave private: wave w stages and reads only c in [64w, 64w+64).
// pb: P [q][s] rows of 72 ushorts: sA pairs at cols 0..31, sB pairs at
//   32..63, alpha float at cols 64-65.
// ---------------------------------------------------------------------------
union __align__(16) SMem {
    struct {
        unsigned short s1[16384];    // 32 KB
        unsigned short s2[16384];    // 32 KB
        unsigned short pb[64][72];   // 9216 B
    } st;                            // 74752 B
    float epi[2][64][68];            // 34816 B, aliases s1 at epilogue
};

__global__ __launch_bounds__(256, 2) void attn_kernel(const unsigned short* __restrict__ qt,
                                                      const unsigned short* __restrict__ sh,
                                                      const unsigned short* __restrict__ sv,
                                                      float* __restrict__ out) {
    __shared__ SMem sm;

    const int t = threadIdx.x;
    const int w = t >> 6;
    const int lane = t & 63;
    const int quad = lane >> 4;
    const int l16 = lane & 15;

    // ---- XCD-affinity decode: all blocks of a given n on one XCD ----
    int qx, b, n;
    {
        const int L = blockIdx.x;          // 0..639
        if (L < 512) {
            n = L & 7;                     // XCD = L % 8 = n
            const int inner = L >> 3;      // 0..63
            b = inner & 3;
            qx = inner >> 2;               // 0..15
        } else {
            const int r = L - 512;         // 0..127
            const int x = r & 7;           // XCD
            n = 8 + (x >> 2);              // 8 on XCD 0-3, 9 on XCD 4-7
            const int combo = (x & 3) * 16 + (r >> 3);   // 0..63
            b = combo & 3;
            qx = combo >> 2;
        }
    }
    const int q0 = qx << 6;
    const int g = n / 5;

    const unsigned short* __restrict__ Shn = sh + (size_t)n * (1024 * 256);
    const unsigned short* __restrict__ Svn = sv + (size_t)n * (256 * 1024);

    // ---- Q A-frags: wave w owns q rows q0+16w .. +15 ----
    f16x8 qf[8];
    {
        const unsigned short* qp = qt + (size_t)(b * 1024 + q0 + 16 * w + l16) * 256 + quad * 8;
#pragma unroll
        for (int f = 0; f < 8; ++f)
            qf[f] = *(const f16x8*)(qp + f * 32);
    }

    // ones A-frag for the row-sum channel
    f16x8 onesA;
#pragma unroll
    for (int j = 0; j < 8; ++j) onesA[j] = (_Float16)1.0f;

    f32x4 O[4][4];   // O^T: c = 64w+16mt+4quad+r, q = 16nt+l16
#pragma unroll
    for (int mt = 0; mt < 4; ++mt)
#pragma unroll
        for (int nt = 0; nt < 4; ++nt) O[mt][nt] = (f32x4){0.f, 0.f, 0.f, 0.f};

    f32x4 Lsum[4];   // row-sum channel: Lsum[nt][*] = sum_s P[q=16nt+l16][s]
#pragma unroll
    for (int nt = 0; nt < 4; ++nt) Lsum[nt] = (f32x4){0.f, 0.f, 0.f, 0.f};

    float m_run[4];
#pragma unroll
    for (int r = 0; r < 4; ++r) m_run[r] = -1e30f;

    for (int s0i = 0; s0i < 16; ++s0i) {
        const int s0 = s0i << 6;

        // ---- DMA-stage s1 (8 groups/wave) and s2 (8 groups/wave) ----
#pragma unroll
        for (int j = 0; j < 8; ++j) {
            const int fidx = 8 * w + j;
            const int half = fidx >> 4, f = (fidx >> 1) & 7, ntp = fidx & 1;
            const unsigned short* g1 = Shn +
                (size_t)(s0 + 32 * half + 2 * l16 + ntp) * 256 + f * 32 + quad * 8;
            gload_lds16(g1, &sm.st.s1[fidx * 512]);
        }
#pragma unroll
        for (int j = 0; j < 8; ++j) {
            const int fidx = 8 * w + j;
            const int c = 64 * w + 8 * j + (lane >> 3);
            const int chunk = (lane & 7) ^ ((lane >> 3) & 7);
            const unsigned short* g2 = Svn + (size_t)c * 1024 + s0 + chunk * 8;
            gload_lds16(g2, &sm.st.s2[fidx * 512]);
        }
        __syncthreads();   // B: drains vmcnt -> tiles ready; fences pb(t-1) reads vs writes

        // ---- QK^T: sim[16q x 64s] ----
        f32x4 sA0 = (f32x4){0.f, 0.f, 0.f, 0.f};
        f32x4 sA1 = (f32x4){0.f, 0.f, 0.f, 0.f};
        f32x4 sB0 = (f32x4){0.f, 0.f, 0.f, 0.f};
        f32x4 sB1 = (f32x4){0.f, 0.f, 0.f, 0.f};
#pragma unroll
        for (int f = 0; f < 8; ++f) {
            const unsigned short* baseA = &sm.st.s1[f * 1024 + quad * 128 + l16 * 8];
            const unsigned short* baseB = baseA + 8192;
            sA0 = __builtin_amdgcn_mfma_f32_16x16x32_f16(qf[f], *(const f16x8*)baseA, sA0, 0, 0, 0);
            sA1 = __builtin_amdgcn_mfma_f32_16x16x32_f16(qf[f], *(const f16x8*)(baseA + 512), sA1, 0, 0, 0);
            sB0 = __builtin_amdgcn_mfma_f32_16x16x32_f16(qf[f], *(const f16x8*)baseB, sB0, 0, 0, 0);
            sB1 = __builtin_amdgcn_mfma_f32_16x16x32_f16(qf[f], *(const f16x8*)(baseB + 512), sB1, 0, 0, 0);
        }

        // ---- online softmax, max only (rows q = 16w+4quad+r; reduce over l16) ----
        float rowmax[4];
#pragma unroll
        for (int r = 0; r < 4; ++r)
            rowmax[r] = fmaxf(fmaxf(sA0[r], sA1[r]), fmaxf(sB0[r], sB1[r]));
#pragma unroll
        for (int off = 1; off <= 8; off <<= 1)
#pragma unroll
            for (int r = 0; r < 4; ++r)
                rowmax[r] = fmaxf(rowmax[r], __shfl_xor(rowmax[r], off, 64));

        float al[4], pA0[4], pA1[4], pB0[4], pB1[4];
#pragma unroll
        for (int r = 0; r < 4; ++r) {
            const float mn = fmaxf(m_run[r], rowmax[r]);
            al[r] = __expf(m_run[r] - mn);
            m_run[r] = mn;
            pA0[r] = __expf(sA0[r] - mn);
            pA1[r] = __expf(sA1[r] - mn);
            pB0[r] = __expf(sB0[r] - mn);
            pB1[r] = __expf(sB1[r] - mn);
        }

        // ---- publish P (fp16 pairs, b32 x2) and alpha (pb cols 64-65) ----
#pragma unroll
        for (int r = 0; r < 4; ++r) {
            union { _Float16 h[2]; unsigned u; } pkA, pkB;
            pkA.h[0] = (_Float16)pA0[r];
            pkA.h[1] = (_Float16)pA1[r];
            pkB.h[0] = (_Float16)pB0[r];
            pkB.h[1] = (_Float16)pB1[r];
            *(unsigned*)&sm.st.pb[16 * w + 4 * quad + r][l16 * 2] = pkA.u;
            *(unsigned*)&sm.st.pb[16 * w + 4 * quad + r][32 + l16 * 2] = pkB.u;
        }
        if (l16 == 0) {
#pragma unroll
            for (int r = 0; r < 4; ++r)
                *(float*)&sm.st.pb[16 * w + 4 * quad + r][64] = al[r];
        }
        __syncthreads();   // C: P ready

        // ---- rescale O^T and Lsum by alpha ----
#pragma unroll
        for (int nt = 0; nt < 4; ++nt) {
            const float a = *(const float*)&sm.st.pb[16 * nt + l16][64];
#pragma unroll
            for (int mt = 0; mt < 4; ++mt) {
                O[mt][nt][0] *= a; O[mt][nt][1] *= a; O[mt][nt][2] *= a; O[mt][nt][3] *= a;
            }
            Lsum[nt][0] *= a; Lsum[nt][1] *= a; Lsum[nt][2] *= a; Lsum[nt][3] *= a;
        }

        // ---- O^T += V^T * P^T;  Lsum += ones * P^T  (two K-chunks) ----
        f16x8 vf[4][2], pf[4][2];
#pragma unroll
        for (int mt = 0; mt < 4; ++mt) {
            const int c = 64 * w + 16 * mt + l16;
#pragma unroll
            for (int ks = 0; ks < 2; ++ks) {
                const int p = c * 8 + ((ks * 4 + quad) ^ (c & 7));
                vf[mt][ks] = *(const f16x8*)&sm.st.s2[p * 8];
            }
        }
#pragma unroll
        for (int nt = 0; nt < 4; ++nt)
#pragma unroll
            for (int ks = 0; ks < 2; ++ks)
                pf[nt][ks] = *(const f16x8*)&sm.st.pb[16 * nt + l16][ks * 32 + quad * 8];
#pragma unroll
        for (int mt = 0; mt < 4; ++mt)
#pragma unroll
            for (int nt = 0; nt < 4; ++nt) {
                O[mt][nt] = __builtin_amdgcn_mfma_f32_16x16x32_f16(vf[mt][0], pf[nt][0], O[mt][nt], 0, 0, 0);
                O[mt][nt] = __builtin_amdgcn_mfma_f32_16x16x32_f16(vf[mt][1], pf[nt][1], O[mt][nt], 0, 0, 0);
            }
#pragma unroll
        for (int nt = 0; nt < 4; ++nt) {
            Lsum[nt] = __builtin_amdgcn_mfma_f32_16x16x32_f16(onesA, pf[nt][0], Lsum[nt], 0, 0, 0);
            Lsum[nt] = __builtin_amdgcn_mfma_f32_16x16x32_f16(onesA, pf[nt][1], Lsum[nt], 0, 0, 0);
        }
    }

    // all final pb/s2 reads done before epi aliases them
    __syncthreads();

    // ---- epilogue: denominator in registers (Lsum), no LDS publish ----
    float linv[4];
#pragma unroll
    for (int nt = 0; nt < 4; ++nt)
        linv[nt] = 0.2f / Lsum[nt][0];

    float* __restrict__ out2 = out + OUT2_OFF + (size_t)((g << 2) + b) * (256 * 1024);

#pragma unroll
    for (int h = 0; h < 2; ++h) {
        if ((w >> 1) == h) {
            const int we = w & 1;
#pragma unroll
            for (int mt = 0; mt < 4; ++mt)
#pragma unroll
                for (int nt = 0; nt < 4; ++nt)
#pragma unroll
                    for (int r = 0; r < 4; ++r)
                        sm.epi[we][16 * mt + 4 * quad + r][16 * nt + l16] = O[mt][nt][r] * linv[nt];
        }
        __syncthreads();
#pragma unroll 4
        for (int i = 0; i < 32; ++i) {
            const int ro = w * 32 + i;   // 0..127 -> c = 128h + ro
            const float v = sm.epi[ro >> 6][ro & 63][lane];
            atomicAdd(out2 + (size_t)(h * 128 + ro) * 1024 + q0 + lane, v);
        }
        __syncthreads();
    }
}

// ---------------------------------------------------------------------------
extern "C" void kernel_launch(void* const* d_in, const int* in_sizes, int n_in,
                              void* d_out, int out_size, void* d_ws, size_t ws_size,
                              hipStream_t stream) {
    const float* q = (const float*)d_in[0];
    const float* s = (const float*)d_in[1];
    float* out = (float*)d_out;
    float* ws = (float*)d_ws;
    unsigned short* sh = (unsigned short*)((char*)d_ws + WS_SH);
    unsigned short* sv = sh + SH_ELEMS;
    unsigned short* qt = sv + SV_ELEMS;

    hipMemsetAsync(d_ws, 0, 2 * sizeof(float), stream);

    means_kernel<<<256, 256, 0, stream>>>(q, s, ws);
    convert_kernel<<<dim3(32, 8, 14), 256, 0, stream>>>(q, s, ws, sh, sv, qt, out);
    attn_kernel<<<640, 256, 0, stream>>>(qt, sh, sv, out);
}

// Round 21
// 206.907 us; speedup vs baseline: 1.2466x; 1.0593x over previous
//
#include <hip/hip_runtime.h>

// B=4, N=10, C=256, Lq=Ls=1024, K=5, G=2.  TQ=64, TS=32.  fp16 MFMA path.
#define CQ_ELEMS (4 * 256 * 1024)
#define CS_ELEMS (10 * 256 * 1024)
#define OUT2_OFF 2097152

typedef __attribute__((ext_vector_type(8))) _Float16 f16x8;
typedef __attribute__((ext_vector_type(4))) float f32x4;

// ws layout (bytes): [0..255] float means[2];
//   Sh[n][s][c] fp16, Sv[n][c][s] fp16, Qt[b][q][c] fp16
#define WS_SH 256
#define SH_ELEMS (10 * 1024 * 256)
#define SV_ELEMS (10 * 256 * 1024)

// direct global->LDS DMA, 16 B per lane; LDS dest = wave-uniform base + lane*16
__device__ __forceinline__ void gload_lds16(const unsigned short* g, unsigned short* l) {
    __builtin_amdgcn_global_load_lds(
        (const __attribute__((address_space(1))) void*)g,
        (__attribute__((address_space(3))) void*)l, 16, 0, 0);
}

// ---------------------------------------------------------------------------
// Grid 1024 (was 256): at 256 blocks = 1 block/CU the streaming reduction is
// latency-bound; 4 blocks/CU quadruples TLP on the HBM read loop (G11).
// ---------------------------------------------------------------------------
__global__ __launch_bounds__(256) void means_kernel(const float* __restrict__ q,
                                                    const float* __restrict__ s,
                                                    float* __restrict__ ws) {
    const int tid = blockIdx.x * 256 + threadIdx.x;
    const int stride = gridDim.x * 256;
    float sq = 0.f, ss = 0.f;
    const float4* q4 = (const float4*)q;
    const float4* s4 = (const float4*)s;
    for (int i = tid; i < CQ_ELEMS / 4; i += stride) {
        float4 v = q4[i];
        sq += (v.x + v.y) + (v.z + v.w);
    }
    for (int i = tid; i < CS_ELEMS / 4; i += stride) {
        float4 v = s4[i];
        ss += (v.x + v.y) + (v.z + v.w);
    }
#pragma unroll
    for (int off = 32; off > 0; off >>= 1) {
        sq += __shfl_down(sq, off, 64);
        ss += __shfl_down(ss, off, 64);
    }
    __shared__ float redq[4], reds[4];
    const int lane = threadIdx.x & 63, wid = threadIdx.x >> 6;
    if (lane == 0) { redq[wid] = sq; reds[wid] = ss; }
    __syncthreads();
    if (threadIdx.x == 0) {
        atomicAdd(&ws[0], (redq[0] + redq[1]) + (redq[2] + redq[3]));
        atomicAdd(&ws[1], (reds[0] + reds[1]) + (reds[2] + reds[3]));
    }
}

// ---------------------------------------------------------------------------
// Centered fp16 conversion.  z<10: S -> Sv [c][s] + Sh [s][c] + zero out2.
// z>=10: Q -> q_out (fp32, both g-copies) + Qt [q][c].
// ---------------------------------------------------------------------------
__global__ __launch_bounds__(256) void convert_kernel(const float* __restrict__ Q,
                                                      const float* __restrict__ S,
                                                      const float* __restrict__ ws,
                                                      unsigned short* __restrict__ sh,
                                                      unsigned short* __restrict__ sv,
                                                      unsigned short* __restrict__ qt,
                                                      float* __restrict__ out) {
    __shared__ unsigned short Th[32][40];
    const int t = threadIdx.x;
    const int x0 = blockIdx.x << 5;   // s (or q) tile base
    const int c0 = blockIdx.y << 5;   // c tile base
    const int z = blockIdx.z;

    const int cl = t >> 3, x4 = (t & 7) << 2;

    if (z < 10) {
        const int n = z;
        const float ms = ws[1] * (1.0f / (float)CS_ELEMS);
        float4 v = *(const float4*)(S + ((size_t)(n * 256 + c0 + cl)) * 1024 + x0 + x4);
        float x[4] = {v.x - ms, v.y - ms, v.z - ms, v.w - ms};
        unsigned short hb[4];
#pragma unroll
        for (int j = 0; j < 4; ++j) {
            _Float16 h = (_Float16)x[j];
            hb[j] = __builtin_bit_cast(unsigned short, h);
            Th[cl][x4 + j] = hb[j];
        }
        *(ushort4*)(sv + ((size_t)(n * 256 + c0 + cl)) * 1024 + x0 + x4) =
            make_ushort4(hb[0], hb[1], hb[2], hb[3]);
        // zero the atomically-accumulated 'aligned' half of d_out (8 MB over 2560 blocks)
        {
            const int lin = (z * 8 + blockIdx.y) * 32 + blockIdx.x;
            const int gid = lin * 256 + t;
            if (gid < 524288) ((int4*)(out + OUT2_OFF))[gid] = make_int4(0, 0, 0, 0);
        }
        __syncthreads();
        const int sl = t >> 3, c4 = (t & 7) << 2;
        *(ushort4*)(sh + ((size_t)(n * 1024 + x0 + sl)) * 256 + c0 + c4) =
            make_ushort4(Th[c4 + 0][sl], Th[c4 + 1][sl], Th[c4 + 2][sl], Th[c4 + 3][sl]);
    } else {
        const int b = z - 10;
        const float mq = ws[0] * (1.0f / (float)CQ_ELEMS);
        float4 v = *(const float4*)(Q + ((size_t)(b * 256 + c0 + cl)) * 1024 + x0 + x4);
        v.x -= mq; v.y -= mq; v.z -= mq; v.w -= mq;
        float* o = out + ((size_t)(b * 2) * 256 + (c0 + cl)) * 1024 + x0 + x4;
        *(float4*)o = v;
        *(float4*)(o + 256 * 1024) = v;
        float x[4] = {v.x, v.y, v.z, v.w};
#pragma unroll
        for (int j = 0; j < 4; ++j) {
            _Float16 h = (_Float16)x[j];
            Th[cl][x4 + j] = __builtin_bit_cast(unsigned short, h);
        }
        __syncthreads();
        const int ql = t >> 3, c4 = (t & 7) << 2;
        *(ushort4*)(qt + ((size_t)(b * 1024 + x0 + ql)) * 256 + c0 + c4) =
            make_ushort4(Th[c4 + 0][ql], Th[c4 + 1][ql], Th[c4 + 2][ql], Th[c4 + 3][ql]);
    }
}

// ---------------------------------------------------------------------------
// Fused flash attention, fp16 MFMA, DMA staging.  = R10 VERBATIM (113.2 us,
// verified twice) -- the attn local optimum.  Design-space map: XCD affinity
// (WIN, FETCH 48.8->16.4 MB), redundant top barrier removed (WIN, 3->2
// barriers), Lsum ones-MFMA row-sum fold (in baseline); REGRESSED: raw-
// barrier/counted-vmcnt schedules (R3/R9/R12), work-duplication splits
// (R6/R14), single-buffer prefetch (R12), TS=64 (R20: drain scales with
// bytes, occupancy loss dominates).  Do not touch the schedule.
//
// Barrier-removal proof:
//   * s1 (K, cross-wave): QK reads(t) < C(t) < DMA writes(t+1); DMA
//     writes(t+1) < B(t+1) < QK reads(t+1).  B drains vmem.
//   * pb (P/alpha, cross-wave): PV reads(t) < B(t+1) < softmax writes(t+1).
//   * s2 (V): per-wave private.
//
// s1 (16 KB): frag-major.  slot16 p = (f*2+nt)*64 + quad*16 + l16 holds
//   Sh[s0 + 2*l16 + nt][f*32 + quad*8 .. +7].
// s2 (16 KB): slot16 p holds V^T[c = p>>2][chunk = (p&3) ^ ((c>>2)&3)];
//   read p = c*4 + (quad ^ ((l16>>2)&3)) -> 2-way (free).
// pb: P [q][s] 80 B rows; alpha at cols 32-33.
// ---------------------------------------------------------------------------
union __align__(16) SMem {
    struct {
        unsigned short s1[8192];     // 16 KB
        unsigned short s2[8192];     // 16 KB
        unsigned short pb[64][40];   // 5 KB (cols 32-33: alpha float)
    } st;
    float epi[2][64][68];            // 34816 B, aliases s1+s2+pb[0..25] at epilogue
};

__global__ __launch_bounds__(256, 3) void attn_kernel(const unsigned short* __restrict__ qt,
                                                      const unsigned short* __restrict__ sh,
                                                      const unsigned short* __restrict__ sv,
                                                      float* __restrict__ out) {
    __shared__ SMem sm;

    const int t = threadIdx.x;
    const int w = t >> 6;
    const int lane = t & 63;
    const int quad = lane >> 4;
    const int l16 = lane & 15;

    // ---- XCD-affinity decode: all blocks of a given n on one XCD ----
    int qx, b, n;
    {
        const int L = blockIdx.x;          // 0..639
        if (L < 512) {
            n = L & 7;                     // XCD = L % 8 = n
            const int inner = L >> 3;      // 0..63
            b = inner & 3;
            qx = inner >> 2;               // 0..15
        } else {
            const int r = L - 512;         // 0..127
            const int x = r & 7;           // XCD
            n = 8 + (x >> 2);              // 8 on XCD 0-3, 9 on XCD 4-7
            const int combo = (x & 3) * 16 + (r >> 3);   // 0..63
            b = combo & 3;
            qx = combo >> 2;
        }
    }
    const int q0 = qx << 6;
    const int g = n / 5;

    const unsigned short* __restrict__ Shn = sh + (size_t)n * (1024 * 256);
    const unsigned short* __restrict__ Svn = sv + (size_t)n * (256 * 1024);

    // ---- Q A-frags: wave w owns q rows q0+16w .. +15 ----
    f16x8 qf[8];
    {
        const unsigned short* qp = qt + (size_t)(b * 1024 + q0 + 16 * w + l16) * 256 + quad * 8;
#pragma unroll
        for (int f = 0; f < 8; ++f)
            qf[f] = *(const f16x8*)(qp + f * 32);
    }

    // ones A-frag for the row-sum channel
    f16x8 onesA;
#pragma unroll
    for (int j = 0; j < 8; ++j) onesA[j] = (_Float16)1.0f;

    f32x4 O[4][4];   // O^T: c = 64w+16mt+4quad+r, q = 16nt+l16
#pragma unroll
    for (int mt = 0; mt < 4; ++mt)
#pragma unroll
        for (int nt = 0; nt < 4; ++nt) O[mt][nt] = (f32x4){0.f, 0.f, 0.f, 0.f};

    f32x4 Lsum[4];   // row-sum channel: Lsum[nt][*] = sum_s P[q=16nt+l16][s]
#pragma unroll
    for (int nt = 0; nt < 4; ++nt) Lsum[nt] = (f32x4){0.f, 0.f, 0.f, 0.f};

    float m_run[4];
#pragma unroll
    for (int r = 0; r < 4; ++r) m_run[r] = -1e30f;

    for (int s0i = 0; s0i < 32; ++s0i) {
        const int s0 = s0i << 5;

        // ---- DMA-stage s1 and s2 (wave w: 4 groups of 64 slots each).
        //      Safe without a top barrier: see dependency proof above. ----
#pragma unroll
        for (int j = 0; j < 4; ++j) {
            const int fidx = 4 * w + j;
            const unsigned short* g1 = Shn +
                (size_t)(s0 + 2 * (lane & 15) + (fidx & 1)) * 256 + (fidx >> 1) * 32 + (lane >> 4) * 8;
            gload_lds16(g1, &sm.st.s1[fidx * 512]);
            const unsigned short* g2 = Svn +
                (size_t)(w * 64 + j * 16 + (lane >> 2)) * 1024 + s0 + ((lane & 3) ^ (lane >> 4)) * 8;
            gload_lds16(g2, &sm.st.s2[fidx * 512]);
        }
        __syncthreads();   // B: drains vmcnt -> tiles ready; also fences pb(t) reads vs writes

        // ---- QK^T: sim[16q x 32s] ----
        f32x4 sim0 = (f32x4){0.f, 0.f, 0.f, 0.f};
        f32x4 sim1 = (f32x4){0.f, 0.f, 0.f, 0.f};
#pragma unroll
        for (int f = 0; f < 8; ++f) {
            const unsigned short* base = &sm.st.s1[f * 1024 + quad * 128 + l16 * 8];
            f16x8 b0 = *(const f16x8*)base;           // nt=0: true s = 2*l16
            f16x8 b1 = *(const f16x8*)(base + 512);   // nt=1: true s = 2*l16+1
            sim0 = __builtin_amdgcn_mfma_f32_16x16x32_f16(qf[f], b0, sim0, 0, 0, 0);
            sim1 = __builtin_amdgcn_mfma_f32_16x16x32_f16(qf[f], b1, sim1, 0, 0, 0);
        }

        // ---- online softmax, max only (rows q = 16w+4quad+r; reduce over l16) ----
        float rowmax[4];
#pragma unroll
        for (int r = 0; r < 4; ++r) rowmax[r] = fmaxf(sim0[r], sim1[r]);
#pragma unroll
        for (int off = 1; off <= 8; off <<= 1)
#pragma unroll
            for (int r = 0; r < 4; ++r)
                rowmax[r] = fmaxf(rowmax[r], __shfl_xor(rowmax[r], off, 64));

        float al[4], pv0[4], pv1[4];
#pragma unroll
        for (int r = 0; r < 4; ++r) {
            const float mn = fmaxf(m_run[r], rowmax[r]);
            al[r] = __expf(m_run[r] - mn);
            m_run[r] = mn;
            pv0[r] = __expf(sim0[r] - mn);
            pv1[r] = __expf(sim1[r] - mn);
        }

        // ---- publish P (fp16 pairs, b32) and alpha (pb cols 32-33) ----
#pragma unroll
        for (int r = 0; r < 4; ++r) {
            union { _Float16 h[2]; unsigned u; } pk;
            pk.h[0] = (_Float16)pv0[r];
            pk.h[1] = (_Float16)pv1[r];
            *(unsigned*)&sm.st.pb[16 * w + 4 * quad + r][l16 * 2] = pk.u;
        }
        if (l16 == 0) {
#pragma unroll
            for (int r = 0; r < 4; ++r)
                *(float*)&sm.st.pb[16 * w + 4 * quad + r][32] = al[r];
        }
        __syncthreads();   // C: P ready

        // ---- rescale O^T and Lsum, then O^T += V^T * P^T; Lsum += ones * P^T ----
#pragma unroll
        for (int nt = 0; nt < 4; ++nt) {
            const float a = *(const float*)&sm.st.pb[16 * nt + l16][32];
#pragma unroll
            for (int mt = 0; mt < 4; ++mt) {
                O[mt][nt][0] *= a; O[mt][nt][1] *= a; O[mt][nt][2] *= a; O[mt][nt][3] *= a;
            }
            Lsum[nt][0] *= a; Lsum[nt][1] *= a; Lsum[nt][2] *= a; Lsum[nt][3] *= a;
        }
        f16x8 vf[4], pf[4];
#pragma unroll
        for (int mt = 0; mt < 4; ++mt) {
            const int c = 64 * w + 16 * mt + l16;
            const int p = c * 4 + (quad ^ ((l16 >> 2) & 3));
            vf[mt] = *(const f16x8*)&sm.st.s2[p * 8];
        }
#pragma unroll
        for (int nt = 0; nt < 4; ++nt)
            pf[nt] = *(const f16x8*)&sm.st.pb[16 * nt + l16][quad * 8];
#pragma unroll
        for (int mt = 0; mt < 4; ++mt)
#pragma unroll
            for (int nt = 0; nt < 4; ++nt)
                O[mt][nt] = __builtin_amdgcn_mfma_f32_16x16x32_f16(vf[mt], pf[nt], O[mt][nt], 0, 0, 0);
#pragma unroll
        for (int nt = 0; nt < 4; ++nt)
            Lsum[nt] = __builtin_amdgcn_mfma_f32_16x16x32_f16(onesA, pf[nt], Lsum[nt], 0, 0, 0);
    }

    // all final pb/s2 reads done before epi aliases them
    __syncthreads();

    // ---- epilogue: denominator in registers (Lsum), no LDS publish ----
    float linv[4];
#pragma unroll
    for (int nt = 0; nt < 4; ++nt)
        linv[nt] = 0.2f / Lsum[nt][0];

    float* __restrict__ out2 = out + OUT2_OFF + (size_t)((g << 2) + b) * (256 * 1024);

#pragma unroll
    for (int h = 0; h < 2; ++h) {
        if ((w >> 1) == h) {
            const int we = w & 1;
#pragma unroll
            for (int mt = 0; mt < 4; ++mt)
#pragma unroll
                for (int nt = 0; nt < 4; ++nt)
#pragma unroll
                    for (int r = 0; r < 4; ++r)
                        sm.epi[we][16 * mt + 4 * quad + r][16 * nt + l16] = O[mt][nt][r] * linv[nt];
        }
        __syncthreads();
#pragma unroll 4
        for (int i = 0; i < 32; ++i) {
            const int ro = w * 32 + i;   // 0..127 -> c = 128h + ro
            const float v = sm.epi[ro >> 6][ro & 63][lane];
            atomicAdd(out2 + (size_t)(h * 128 + ro) * 1024 + q0 + lane, v);
        }
        __syncthreads();
    }
}

// ---------------------------------------------------------------------------
extern "C" void kernel_launch(void* const* d_in, const int* in_sizes, int n_in,
                              void* d_out, int out_size, void* d_ws, size_t ws_size,
                              hipStream_t stream) {
    const float* q = (const float*)d_in[0];
    const float* s = (const float*)d_in[1];
    float* out = (float*)d_out;
    float* ws = (float*)d_ws;
    unsigned short* sh = (unsigned short*)((char*)d_ws + WS_SH);
    unsigned short* sv = sh + SH_ELEMS;
    unsigned short* qt = sv + SV_ELEMS;

    hipMemsetAsync(d_ws, 0, 2 * sizeof(float), stream);

    means_kernel<<<1024, 256, 0, stream>>>(q, s, ws);
    convert_kernel<<<dim3(32, 8, 14), 256, 0, stream>>>(q, s, ws, sh, sv, qt, out);
    attn_kernel<<<640, 256, 0, stream>>>(qt, sh, sv, out);
}